// Round 7
// baseline (91.942 us; speedup 1.0000x reference)
//
#include <hip/hip_runtime.h>
#include <math.h>

#define FDIM 512
#define NL 1600
#define NR 64

typedef __attribute__((ext_vector_type(8))) short short8;      // 8 bf16 = 4 VGPR (MFMA A/B frag)
typedef __attribute__((ext_vector_type(4))) float f32x4;       // MFMA C/D frag
typedef __attribute__((ext_vector_type(8))) unsigned short ushort8;
typedef __attribute__((ext_vector_type(4))) unsigned short ushort4v;

__device__ __forceinline__ unsigned short f2bf(float f) {
    unsigned u = __float_as_uint(f);
    u += 0x7fffu + ((u >> 16) & 1u);   // RNE
    return (unsigned short)(u >> 16);
}

// K1 (prep), 520 role-split blocks x 256 thr:
//   b 0..255  : transpose+convert W1top -> WT[512][512] bf16, WT[n][k] = W1[k][n]
//   b 256..455: gather+convert 8 fl rows each -> Abf[1600][512] bf16
//   b 456..519: Bm[r][n] = b1[n] + sum_k fr[r][k]*W1[512+k][n]  (f32 vector GEMM, exact)
//               block 456 also: wd[k] = W2[k][1] - W2[k][0]
__global__ __launch_bounds__(256) void k_prep(
    const float* __restrict__ SL, const float* __restrict__ SR,
    const float* __restrict__ W1, const float* __restrict__ W2,
    const float* __restrict__ b1,
    const int* __restrict__ idxL, const int* __restrict__ idxR,
    unsigned short* __restrict__ Abf, unsigned short* __restrict__ WT,
    float* __restrict__ Bm, float* __restrict__ wd)
{
    __shared__ float tile[32][33];
    const int t = threadIdx.x;
    const int b = blockIdx.x;
    if (b < 256) {
        const int kt = b >> 4, nt = b & 15;
        const int r  = t >> 3, c4 = (t & 7) << 2;
        float4 v = *(const float4*)(&W1[(long)(kt*32 + r) * FDIM + nt*32 + c4]);
        tile[r][c4+0]=v.x; tile[r][c4+1]=v.y; tile[r][c4+2]=v.z; tile[r][c4+3]=v.w;
        __syncthreads();
        const int nl = t >> 3, k4 = (t & 7) << 2;
        ushort4v o;
        o[0]=f2bf(tile[k4+0][nl]); o[1]=f2bf(tile[k4+1][nl]);
        o[2]=f2bf(tile[k4+2][nl]); o[3]=f2bf(tile[k4+3][nl]);
        *(ushort4v*)(&WT[(long)(nt*32 + nl)*FDIM + kt*32 + k4]) = o;
    } else if (b < 456) {
        const int row = (b - 256) * 8 + (t >> 5);
        const int k0  = (t & 31) * 16;
        const float* p = SL + (long)idxL[row] * FDIM + k0;
        float4 v0 = *(const float4*)(p);
        float4 v1 = *(const float4*)(p + 4);
        float4 v2 = *(const float4*)(p + 8);
        float4 v3 = *(const float4*)(p + 12);
        ushort8 o0, o1;
        o0[0]=f2bf(v0.x); o0[1]=f2bf(v0.y); o0[2]=f2bf(v0.z); o0[3]=f2bf(v0.w);
        o0[4]=f2bf(v1.x); o0[5]=f2bf(v1.y); o0[6]=f2bf(v1.z); o0[7]=f2bf(v1.w);
        o1[0]=f2bf(v2.x); o1[1]=f2bf(v2.y); o1[2]=f2bf(v2.z); o1[3]=f2bf(v2.w);
        o1[4]=f2bf(v3.x); o1[5]=f2bf(v3.y); o1[6]=f2bf(v3.z); o1[7]=f2bf(v3.w);
        *(ushort8*)(Abf + (long)row * FDIM + k0)     = o0;
        *(ushort8*)(Abf + (long)row * FDIM + k0 + 8) = o1;
    } else {
        const int q  = b - 456;                 // 0..63
        const int rg = q >> 3, ng = q & 7;
        const int w  = t >> 6, lane = t & 63;
        const int r0 = rg * 8 + w * 2;          // wave-uniform row pair
        const int n  = ng * 64 + lane;
        const float* f0 = SR + (long)idxR[r0]     * FDIM;
        const float* f1 = SR + (long)idxR[r0 + 1] * FDIM;
        const float* wp = W1 + (long)FDIM * FDIM + n;   // W1[512+k][n]
        float a0 = 0.f, a1 = 0.f;
        #pragma unroll 8
        for (int k = 0; k < FDIM; ++k) {
            float wv = wp[(long)k * FDIM];
            a0 = fmaf(f0[k], wv, a0);
            a1 = fmaf(f1[k], wv, a1);
        }
        const float bb = b1[n];
        Bm[(long)r0 * FDIM + n]       = a0 + bb;
        Bm[(long)(r0 + 1) * FDIM + n] = a1 + bb;
        if (q == 0) {
            float4 v = *(const float4*)(&W2[t * 4]);   // k = 2t, 2t+1
            wd[2*t]   = v.y - v.x;
            wd[2*t+1] = v.w - v.z;
        }
    }
}

// K2 (fused): 200 blocks x 512 thr (8 waves). Block owns 8 l-rows.
//  phase M: A-tile[8][512] = Abf[lb..lb+7] @ W1top  via MFMA (wave w -> n-cols w*64..+63;
//           A-rows duplicated into m=8..15 via row&7, dup outputs dropped at store).
//           Stored to global Ag (block-local RAW; threadfence+syncthreads).
//  stage:   Bm f32 -> LDS bf16 Bs[64][128] uint2, unit-XOR (u ^ (r&15)) -> 4-way reads.
//  phase P: wave w: l-group (w&1)*4 (4 rows), k-chunk (w>>1)*128. lane = r.
//           A/wd wave-uniform VMEM float4 (L2-hot); B from LDS.
//  epilogue: LDS partial reduce over 4 k-chunks + sigmoid -> out.
__global__ __launch_bounds__(512) void k_fused(
    const short* __restrict__ Abf, const short* __restrict__ WT,
    const float* __restrict__ Bm, const float* __restrict__ wd,
    const float* __restrict__ b2,
    float* __restrict__ Ag, float* __restrict__ out)
{
    __shared__ uint2 Bs[NR][128];   // 64 KB, aliased as Part[4][2][4][64] f32 in epilogue
    const int t    = threadIdx.x;
    const int w    = t >> 6;        // 0..7
    const int lane = t & 63;
    const int lb   = blockIdx.x * 8;

    // ---------- phase M ----------
    {
        const int row = lane & 15, g = lane >> 4;
        const int n0  = w * 64;
        const short* aP = Abf + (long)(lb + (row & 7)) * FDIM + g * 8;
        const short* bP = WT  + (long)(n0 + row) * FDIM + g * 8;
        f32x4 acc[4] = {};
        short8 a[3], bf[3][4];
        #pragma unroll
        for (int s = 0; s < 3; ++s) {
            a[s] = *(const short8*)(aP + s * 32);
            #pragma unroll
            for (int j = 0; j < 4; ++j)
                bf[s][j] = *(const short8*)(bP + s * 32 + j * 16 * FDIM);
        }
        #pragma unroll
        for (int kk = 0; kk < 16; ++kk) {
            const int cur = kk % 3;        // compile-time after full unroll
            #pragma unroll
            for (int j = 0; j < 4; ++j)
                acc[j] = __builtin_amdgcn_mfma_f32_16x16x32_bf16(a[cur], bf[cur][j], acc[j], 0, 0, 0);
            if (kk < 13) {
                const int ko = (kk + 3) * 32;
                a[cur] = *(const short8*)(aP + ko);
                #pragma unroll
                for (int j = 0; j < 4; ++j)
                    bf[cur][j] = *(const short8*)(bP + ko + j * 16 * FDIM);
            }
        }
        if (g < 2) {   // m = g*4+r in 0..7 are the real rows; 8..15 are duplicates
            #pragma unroll
            for (int j = 0; j < 4; ++j)
                #pragma unroll
                for (int r = 0; r < 4; ++r)
                    Ag[(long)(lb + g*4 + r) * FDIM + n0 + j*16 + row] = acc[j][r];
        }
    }
    __threadfence();     // drain stores; block-local global RAW
    __syncthreads();

    // ---------- stage B -> LDS bf16 ----------
    {
        const float4* B4 = (const float4*)Bm;
        const int r = t >> 3;                  // 0..63
        #pragma unroll
        for (int i = 0; i < 16; ++i) {
            const int u = (t & 7) * 16 + i;    // b64 unit 0..127 (4 bf16 = 1 k4)
            float4 v = B4[r * 128 + u];
            unsigned lo = (unsigned)f2bf(v.x) | ((unsigned)f2bf(v.y) << 16);
            unsigned hi = (unsigned)f2bf(v.z) | ((unsigned)f2bf(v.w) << 16);
            Bs[r][u ^ (r & 15)] = make_uint2(lo, hi);
        }
    }
    __syncthreads();

    // ---------- phase P ----------
    const int lg = w & 1, ch = w >> 1;
    const int l0 = lb + lg * 4;
    const float4* A0 = (const float4*)(Ag + (long)(l0 + 0) * FDIM) + ch * 32;
    const float4* A1 = (const float4*)(Ag + (long)(l0 + 1) * FDIM) + ch * 32;
    const float4* A2 = (const float4*)(Ag + (long)(l0 + 2) * FDIM) + ch * 32;
    const float4* A3 = (const float4*)(Ag + (long)(l0 + 3) * FDIM) + ch * 32;
    const float4* Wp = (const float4*)wd + ch * 32;
    float s0 = 0.f, s1 = 0.f, s2 = 0.f, s3 = 0.f;
    #pragma unroll 4
    for (int i = 0; i < 32; ++i) {
        uint2 pk = Bs[lane][(ch * 32 + i) ^ (lane & 15)];
        float bx = __uint_as_float(pk.x << 16);
        float by = __uint_as_float(pk.x & 0xffff0000u);
        float bz = __uint_as_float(pk.y << 16);
        float bw = __uint_as_float(pk.y & 0xffff0000u);
        float4 wv = Wp[i];
        float4 a0 = A0[i], a1 = A1[i], a2 = A2[i], a3 = A3[i];
        s0 = fmaf(fmaxf(a0.x + bx, 0.f), wv.x, s0);
        s0 = fmaf(fmaxf(a0.y + by, 0.f), wv.y, s0);
        s0 = fmaf(fmaxf(a0.z + bz, 0.f), wv.z, s0);
        s0 = fmaf(fmaxf(a0.w + bw, 0.f), wv.w, s0);
        s1 = fmaf(fmaxf(a1.x + bx, 0.f), wv.x, s1);
        s1 = fmaf(fmaxf(a1.y + by, 0.f), wv.y, s1);
        s1 = fmaf(fmaxf(a1.z + bz, 0.f), wv.z, s1);
        s1 = fmaf(fmaxf(a1.w + bw, 0.f), wv.w, s1);
        s2 = fmaf(fmaxf(a2.x + bx, 0.f), wv.x, s2);
        s2 = fmaf(fmaxf(a2.y + by, 0.f), wv.y, s2);
        s2 = fmaf(fmaxf(a2.z + bz, 0.f), wv.z, s2);
        s2 = fmaf(fmaxf(a2.w + bw, 0.f), wv.w, s2);
        s3 = fmaf(fmaxf(a3.x + bx, 0.f), wv.x, s3);
        s3 = fmaf(fmaxf(a3.y + by, 0.f), wv.y, s3);
        s3 = fmaf(fmaxf(a3.z + bz, 0.f), wv.z, s3);
        s3 = fmaf(fmaxf(a3.w + bw, 0.f), wv.w, s3);
    }
    __syncthreads();                       // all Bs reads done before aliasing
    float* Part = (float*)Bs;              // [ch][lg][li][r] = [4][2][4][64]
    {
        const int base = ((ch * 2 + lg) * 4) * 64 + lane;
        Part[base]       = s0;
        Part[base + 64]  = s1;
        Part[base + 128] = s2;
        Part[base + 192] = s3;
    }
    __syncthreads();

    // ---------- epilogue: reduce + sigmoid ----------
    {
        const int l8 = t >> 6, rr = t & 63;        // 512 threads = 8 l x 64 r
        const int plg = l8 >> 2, pli = l8 & 3;
        float sum = b2[1] - b2[0];
        #pragma unroll
        for (int c = 0; c < 4; ++c)
            sum += Part[((c * 2 + plg) * 4 + pli) * 64 + rr];
        out[(long)(lb + l8) * NR + rr] = 1.f / (1.f + expf(-sum));
    }
}

extern "C" void kernel_launch(void* const* d_in, const int* in_sizes, int n_in,
                              void* d_out, int out_size, void* d_ws, size_t ws_size,
                              hipStream_t stream) {
    const float* SL  = (const float*)d_in[0];   // [200000,512]
    const float* SR  = (const float*)d_in[1];   // [100000,512]
    const float* W1  = (const float*)d_in[2];   // [1024,512]
    const float* b1  = (const float*)d_in[3];   // [512]
    const float* W2  = (const float*)d_in[4];   // [512,2]
    const float* b2  = (const float*)d_in[5];   // [2]
    const int*   idxL = (const int*)d_in[6];    // [1600]
    const int*   idxR = (const int*)d_in[7];    // [64]
    float* out = (float*)d_out;                 // [1600,64]

    float* Ag = (float*)d_ws;                          // [1600,512] f32
    float* Bm = Ag + (long)NL * FDIM;                  // [64,512]   f32
    float* wd = Bm + (long)NR * FDIM;                  // [512]      f32
    unsigned short* Abf = (unsigned short*)(wd + FDIM);   // [1600,512] bf16
    unsigned short* WT  = Abf + (long)NL * FDIM;          // [512,512]  bf16

    k_prep<<<520, 256, 0, stream>>>(SL, SR, W1, W2, b1, idxL, idxR, Abf, WT, Bm, wd);
    k_fused<<<200, 512, 0, stream>>>((const short*)Abf, (const short*)WT, Bm, wd, b2, Ag, out);
}

// Round 8
// 48.316 us; speedup vs baseline: 1.9029x; 1.9029x over previous
//
#include <hip/hip_runtime.h>
#include <math.h>

#define FDIM 512
#define NL 1600
#define NR 64

typedef __attribute__((ext_vector_type(8))) short short8;      // 8 bf16 = 4 VGPR (MFMA A/B frag)
typedef __attribute__((ext_vector_type(4))) float f32x4;       // MFMA C/D frag
typedef __attribute__((ext_vector_type(8))) unsigned short ushort8;
typedef __attribute__((ext_vector_type(4))) unsigned short ushort4v;

__device__ __forceinline__ unsigned short f2bf(float f) {
    unsigned u = __float_as_uint(f);
    u += 0x7fffu + ((u >> 16) & 1u);   // RNE
    return (unsigned short)(u >> 16);
}

// K1 (prep), 520 role-split blocks x 256 thr — UNCHANGED from round 7:
//   b 0..255  : transpose+convert W1top -> WT[512][512] bf16, WT[n][k] = W1[k][n]
//   b 256..455: gather+convert 8 fl rows each -> Abf[1600][512] bf16
//   b 456..519: Bm[r][n] = b1[n] + sum_k fr[r][k]*W1[512+k][n]  (f32 vector GEMM, exact)
//               block 456 also: wd[k] = W2[k][1] - W2[k][0]
__global__ __launch_bounds__(256) void k_prep(
    const float* __restrict__ SL, const float* __restrict__ SR,
    const float* __restrict__ W1, const float* __restrict__ W2,
    const float* __restrict__ b1,
    const int* __restrict__ idxL, const int* __restrict__ idxR,
    unsigned short* __restrict__ Abf, unsigned short* __restrict__ WT,
    float* __restrict__ Bm, float* __restrict__ wd)
{
    __shared__ float tile[32][33];
    const int t = threadIdx.x;
    const int b = blockIdx.x;
    if (b < 256) {
        const int kt = b >> 4, nt = b & 15;
        const int r  = t >> 3, c4 = (t & 7) << 2;
        float4 v = *(const float4*)(&W1[(long)(kt*32 + r) * FDIM + nt*32 + c4]);
        tile[r][c4+0]=v.x; tile[r][c4+1]=v.y; tile[r][c4+2]=v.z; tile[r][c4+3]=v.w;
        __syncthreads();
        const int nl = t >> 3, k4 = (t & 7) << 2;
        ushort4v o;
        o[0]=f2bf(tile[k4+0][nl]); o[1]=f2bf(tile[k4+1][nl]);
        o[2]=f2bf(tile[k4+2][nl]); o[3]=f2bf(tile[k4+3][nl]);
        *(ushort4v*)(&WT[(long)(nt*32 + nl)*FDIM + kt*32 + k4]) = o;
    } else if (b < 456) {
        const int row = (b - 256) * 8 + (t >> 5);
        const int k0  = (t & 31) * 16;
        const float* p = SL + (long)idxL[row] * FDIM + k0;
        float4 v0 = *(const float4*)(p);
        float4 v1 = *(const float4*)(p + 4);
        float4 v2 = *(const float4*)(p + 8);
        float4 v3 = *(const float4*)(p + 12);
        ushort8 o0, o1;
        o0[0]=f2bf(v0.x); o0[1]=f2bf(v0.y); o0[2]=f2bf(v0.z); o0[3]=f2bf(v0.w);
        o0[4]=f2bf(v1.x); o0[5]=f2bf(v1.y); o0[6]=f2bf(v1.z); o0[7]=f2bf(v1.w);
        o1[0]=f2bf(v2.x); o1[1]=f2bf(v2.y); o1[2]=f2bf(v2.z); o1[3]=f2bf(v2.w);
        o1[4]=f2bf(v3.x); o1[5]=f2bf(v3.y); o1[6]=f2bf(v3.z); o1[7]=f2bf(v3.w);
        *(ushort8*)(Abf + (long)row * FDIM + k0)     = o0;
        *(ushort8*)(Abf + (long)row * FDIM + k0 + 8) = o1;
    } else {
        const int q  = b - 456;                 // 0..63
        const int rg = q >> 3, ng = q & 7;
        const int w  = t >> 6, lane = t & 63;
        const int r0 = rg * 8 + w * 2;          // wave-uniform row pair
        const int n  = ng * 64 + lane;
        const float* f0 = SR + (long)idxR[r0]     * FDIM;
        const float* f1 = SR + (long)idxR[r0 + 1] * FDIM;
        const float* wp = W1 + (long)FDIM * FDIM + n;   // W1[512+k][n]
        float a0 = 0.f, a1 = 0.f;
        #pragma unroll 8
        for (int k = 0; k < FDIM; ++k) {
            float wv = wp[(long)k * FDIM];
            a0 = fmaf(f0[k], wv, a0);
            a1 = fmaf(f1[k], wv, a1);
        }
        const float bb = b1[n];
        Bm[(long)r0 * FDIM + n]       = a0 + bb;
        Bm[(long)(r0 + 1) * FDIM + n] = a1 + bb;
        if (q == 0) {
            float4 v = *(const float4*)(&W2[t * 4]);   // k = 2t, 2t+1
            wd[2*t]   = v.y - v.x;
            wd[2*t+1] = v.w - v.z;
        }
    }
}

// K2 (fused): 200 blocks x 512 thr (8 waves). Block owns 8 l-rows.
//  phase M: A-tile[8][512] via MFMA -> LDS Asm (16 KB; NO global round trip,
//           NO threadfence — the R7 killer). MFMA stores are 2-row/16-col
//           pattern = 2-way bank alias = free (m136).
//  stage:   Bm f32 -> LDS bf16 Bs[64][128] uint2, unit-XOR (u ^ (r&15)).
//  phase P: wave w: l-group (w&1)*4, k-chunk (w>>1)*128; lane = r.
//           A from LDS broadcast reads; wd wave-uniform global; B from LDS.
//  epilogue: LDS partial reduce over 4 k-chunks + sigmoid -> out.
__global__ __launch_bounds__(512) void k_fused(
    const short* __restrict__ Abf, const short* __restrict__ WT,
    const float* __restrict__ Bm, const float* __restrict__ wd,
    const float* __restrict__ b2, float* __restrict__ out)
{
    __shared__ uint2 Bs[NR][128];   // 64 KB, aliased as Part[4][2][4][64] f32 in epilogue
    __shared__ float Asm[8][FDIM];  // 16 KB A-tile
    const int t    = threadIdx.x;
    const int w    = t >> 6;        // 0..7
    const int lane = t & 63;
    const int lb   = blockIdx.x * 8;

    // ---------- phase M ----------
    {
        const int row = lane & 15, g = lane >> 4;
        const int n0  = w * 64;
        const short* aP = Abf + (long)(lb + (row & 7)) * FDIM + g * 8;
        const short* bP = WT  + (long)(n0 + row) * FDIM + g * 8;
        f32x4 acc[4] = {};
        short8 a[3], bf[3][4];
        #pragma unroll
        for (int s = 0; s < 3; ++s) {
            a[s] = *(const short8*)(aP + s * 32);
            #pragma unroll
            for (int j = 0; j < 4; ++j)
                bf[s][j] = *(const short8*)(bP + s * 32 + j * 16 * FDIM);
        }
        #pragma unroll
        for (int kk = 0; kk < 16; ++kk) {
            const int cur = kk % 3;        // compile-time after full unroll
            #pragma unroll
            for (int j = 0; j < 4; ++j)
                acc[j] = __builtin_amdgcn_mfma_f32_16x16x32_bf16(a[cur], bf[cur][j], acc[j], 0, 0, 0);
            if (kk < 13) {
                const int ko = (kk + 3) * 32;
                a[cur] = *(const short8*)(aP + ko);
                #pragma unroll
                for (int j = 0; j < 4; ++j)
                    bf[cur][j] = *(const short8*)(bP + ko + j * 16 * FDIM);
            }
        }
        if (g < 2) {   // m = g*4+r in 0..7 are real rows; 8..15 are duplicates
            #pragma unroll
            for (int j = 0; j < 4; ++j)
                #pragma unroll
                for (int r = 0; r < 4; ++r)
                    Asm[g*4 + r][n0 + j*16 + row] = acc[j][r];
        }
    }

    // ---------- stage B -> LDS bf16 (independent of phase M) ----------
    {
        const float4* B4 = (const float4*)Bm;
        const int r = t >> 3;                  // 0..63
        #pragma unroll
        for (int i = 0; i < 16; ++i) {
            const int u = (t & 7) * 16 + i;    // b64 unit 0..127 (4 bf16 = 1 k4)
            float4 v = B4[r * 128 + u];
            unsigned lo = (unsigned)f2bf(v.x) | ((unsigned)f2bf(v.y) << 16);
            unsigned hi = (unsigned)f2bf(v.z) | ((unsigned)f2bf(v.w) << 16);
            Bs[r][u ^ (r & 15)] = make_uint2(lo, hi);
        }
    }
    __syncthreads();   // Asm + Bs both visible

    // ---------- phase P ----------
    const int lg = w & 1, ch = w >> 1;
    const float4* A0 = (const float4*)&Asm[lg*4 + 0][ch * 128];
    const float4* A1 = (const float4*)&Asm[lg*4 + 1][ch * 128];
    const float4* A2 = (const float4*)&Asm[lg*4 + 2][ch * 128];
    const float4* A3 = (const float4*)&Asm[lg*4 + 3][ch * 128];
    const float4* Wp = (const float4*)wd + ch * 32;
    float s0 = 0.f, s1 = 0.f, s2 = 0.f, s3 = 0.f;
    #pragma unroll 4
    for (int i = 0; i < 32; ++i) {
        uint2 pk = Bs[lane][(ch * 32 + i) ^ (lane & 15)];
        float bx = __uint_as_float(pk.x << 16);
        float by = __uint_as_float(pk.x & 0xffff0000u);
        float bz = __uint_as_float(pk.y << 16);
        float bw = __uint_as_float(pk.y & 0xffff0000u);
        float4 wv = Wp[i];
        float4 a0 = A0[i], a1 = A1[i], a2 = A2[i], a3 = A3[i];
        s0 = fmaf(fmaxf(a0.x + bx, 0.f), wv.x, s0);
        s0 = fmaf(fmaxf(a0.y + by, 0.f), wv.y, s0);
        s0 = fmaf(fmaxf(a0.z + bz, 0.f), wv.z, s0);
        s0 = fmaf(fmaxf(a0.w + bw, 0.f), wv.w, s0);
        s1 = fmaf(fmaxf(a1.x + bx, 0.f), wv.x, s1);
        s1 = fmaf(fmaxf(a1.y + by, 0.f), wv.y, s1);
        s1 = fmaf(fmaxf(a1.z + bz, 0.f), wv.z, s1);
        s1 = fmaf(fmaxf(a1.w + bw, 0.f), wv.w, s1);
        s2 = fmaf(fmaxf(a2.x + bx, 0.f), wv.x, s2);
        s2 = fmaf(fmaxf(a2.y + by, 0.f), wv.y, s2);
        s2 = fmaf(fmaxf(a2.z + bz, 0.f), wv.z, s2);
        s2 = fmaf(fmaxf(a2.w + bw, 0.f), wv.w, s2);
        s3 = fmaf(fmaxf(a3.x + bx, 0.f), wv.x, s3);
        s3 = fmaf(fmaxf(a3.y + by, 0.f), wv.y, s3);
        s3 = fmaf(fmaxf(a3.z + bz, 0.f), wv.z, s3);
        s3 = fmaf(fmaxf(a3.w + bw, 0.f), wv.w, s3);
    }
    __syncthreads();                       // all Bs reads done before aliasing
    float* Part = (float*)Bs;              // [ch][lg][li][r] = [4][2][4][64]
    {
        const int base = ((ch * 2 + lg) * 4) * 64 + lane;
        Part[base]       = s0;
        Part[base + 64]  = s1;
        Part[base + 128] = s2;
        Part[base + 192] = s3;
    }
    __syncthreads();

    // ---------- epilogue: reduce + sigmoid ----------
    {
        const int l8 = t >> 6, rr = t & 63;        // 512 threads = 8 l x 64 r
        const int plg = l8 >> 2, pli = l8 & 3;
        float sum = b2[1] - b2[0];
        #pragma unroll
        for (int c = 0; c < 4; ++c)
            sum += Part[((c * 2 + plg) * 4 + pli) * 64 + rr];
        out[(long)(lb + l8) * NR + rr] = 1.f / (1.f + expf(-sum));
    }
}

extern "C" void kernel_launch(void* const* d_in, const int* in_sizes, int n_in,
                              void* d_out, int out_size, void* d_ws, size_t ws_size,
                              hipStream_t stream) {
    const float* SL  = (const float*)d_in[0];   // [200000,512]
    const float* SR  = (const float*)d_in[1];   // [100000,512]
    const float* W1  = (const float*)d_in[2];   // [1024,512]
    const float* b1  = (const float*)d_in[3];   // [512]
    const float* W2  = (const float*)d_in[4];   // [512,2]
    const float* b2  = (const float*)d_in[5];   // [2]
    const int*   idxL = (const int*)d_in[6];    // [1600]
    const int*   idxR = (const int*)d_in[7];    // [64]
    float* out = (float*)d_out;                 // [1600,64]

    float* Bm = (float*)d_ws;                          // [64,512] f32
    float* wd = Bm + (long)NR * FDIM;                  // [512]    f32
    unsigned short* Abf = (unsigned short*)(wd + FDIM);   // [1600,512] bf16
    unsigned short* WT  = Abf + (long)NL * FDIM;          // [512,512]  bf16

    k_prep<<<520, 256, 0, stream>>>(SL, SR, W1, W2, b1, idxL, idxR, Abf, WT, Bm, wd);
    k_fused<<<200, 512, 0, stream>>>((const short*)Abf, (const short*)WT, Bm, wd, b2, out);
}

// Round 9
// 40.358 us; speedup vs baseline: 2.2782x; 1.1972x over previous
//
#include <hip/hip_runtime.h>
#include <math.h>

#define FDIM 512
#define NL 1600
#define NR 64
#define NM (NL + NR)   // 1664 gathered rows

typedef __attribute__((ext_vector_type(8))) short short8;      // 8 bf16 = 4 VGPR (MFMA A/B frag)
typedef __attribute__((ext_vector_type(4))) float f32x4;       // MFMA C/D frag
typedef __attribute__((ext_vector_type(8))) unsigned short ushort8;
typedef __attribute__((ext_vector_type(4))) unsigned short ushort4v;

__device__ __forceinline__ unsigned short f2bf(float f) {
    unsigned u = __float_as_uint(f);
    u += 0x7fffu + ((u >> 16) & 1u);   // RNE
    return (unsigned short)(u >> 16);
}

// K1 (prep) — R4-proven, 929 blocks x 256 thr:
//  blocks 0..415  : gather+convert 4 rows each -> Abf[1664][512] bf16
//  blocks 416..927: transpose+convert W1 -> WT[2][512][512] bf16, WT[h][n][k] = W1[h*512+k][n]
//  block  928     : wd[k] = W2[k][1] - W2[k][0]
__global__ __launch_bounds__(256) void k_prep(
    const float* __restrict__ SL, const float* __restrict__ SR,
    const float* __restrict__ W1, const float* __restrict__ W2,
    const int* __restrict__ idxL, const int* __restrict__ idxR,
    unsigned short* __restrict__ Abf, unsigned short* __restrict__ WT,
    float* __restrict__ wd)
{
    __shared__ float tile[32][33];
    const int t = threadIdx.x;
    if (blockIdx.x == 928) {
        float4 v = *(const float4*)(&W2[t * 4]);   // k = 2t, 2t+1
        wd[2 * t]     = v.y - v.x;
        wd[2 * t + 1] = v.w - v.z;
        return;
    }
    if (blockIdx.x < 416) {
        const int rowi = blockIdx.x * 4 + (t >> 6);
        const int k0 = (t & 63) * 8;
        long srow; const float* sp;
        if (rowi < NL) { srow = idxL[rowi];      sp = SL; }
        else           { srow = idxR[rowi - NL]; sp = SR; }
        const float* p = sp + srow * FDIM + k0;
        float4 v0 = *(const float4*)(p);
        float4 v1 = *(const float4*)(p + 4);
        ushort8 o;
        o[0]=f2bf(v0.x); o[1]=f2bf(v0.y); o[2]=f2bf(v0.z); o[3]=f2bf(v0.w);
        o[4]=f2bf(v1.x); o[5]=f2bf(v1.y); o[6]=f2bf(v1.z); o[7]=f2bf(v1.w);
        *(ushort8*)(Abf + (long)rowi * FDIM + k0) = o;
    } else {
        const int bidx = blockIdx.x - 416;
        const int ktile = bidx >> 4;   // 0..31 over fk (1024/32)
        const int ntile = bidx & 15;   // 0..15 over n  (512/32)
        {
            const int r  = t >> 3;         // 0..31 (fk offset)
            const int c4 = (t & 7) << 2;   // 0..28 (n offset)
            float4 v = *(const float4*)(&W1[(long)(ktile*32 + r) * FDIM + ntile*32 + c4]);
            tile[r][c4+0]=v.x; tile[r][c4+1]=v.y; tile[r][c4+2]=v.z; tile[r][c4+3]=v.w;
        }
        __syncthreads();
        const int h  = ktile >> 4;               // which half of W1 (top/bot)
        const int kb = (ktile & 15) * 32;        // k base within half
        const int nl = t >> 3;                   // 0..31
        const int k4 = (t & 7) * 4;
        ushort4v o;
        o[0]=f2bf(tile[k4+0][nl]); o[1]=f2bf(tile[k4+1][nl]);
        o[2]=f2bf(tile[k4+2][nl]); o[3]=f2bf(tile[k4+3][nl]);
        *(ushort4v*)(WT + (long)h*FDIM*FDIM + (long)(ntile*32 + nl)*FDIM + kb + k4) = o;
    }
}

// K2 (MFMA GEMM) — R4-proven verbatim. 1 wave/block, tile 32(M) x 64(N), K=512,
// depth-6 register pipeline. bm 0..49 -> A rows, bm 50..51 -> Bm rows (+b1).
__global__ __launch_bounds__(64) void k_mfma(
    const short* __restrict__ Abf, const short* __restrict__ WT,
    const float* __restrict__ b1, float* __restrict__ A, float* __restrict__ Bm)
{
    const int bm = blockIdx.x;     // 0..51
    const int bn = blockIdx.y;     // 0..7
    const bool isB = bm >= 50;
    const int m0 = bm * 32, n0 = bn * 64;
    const short* wt = WT + (isB ? (long)FDIM * FDIM : 0);
    const int lane = threadIdx.x;
    const int row = lane & 15, g = lane >> 4;

    f32x4 acc[2][4] = {};
    const short* aP = Abf + (long)(m0 + row) * FDIM + g * 8;
    const short* bP = wt  + (long)(n0 + row) * FDIM + g * 8;

    short8 a[6][2], b[6][4];
    #pragma unroll
    for (int s = 0; s < 6; ++s) {
        #pragma unroll
        for (int i = 0; i < 2; i++) a[s][i] = *(const short8*)(aP + s * 32 + i * 16 * FDIM);
        #pragma unroll
        for (int j = 0; j < 4; j++) b[s][j] = *(const short8*)(bP + s * 32 + j * 16 * FDIM);
    }

    #pragma unroll
    for (int kk = 0; kk < 16; ++kk) {
        const int cur = kk % 6;                 // compile-time after full unroll
        #pragma unroll
        for (int i = 0; i < 2; i++)
            #pragma unroll
            for (int j = 0; j < 4; j++)
                acc[i][j] = __builtin_amdgcn_mfma_f32_16x16x32_bf16(a[cur][i], b[cur][j], acc[i][j], 0, 0, 0);
        if (kk < 10) {
            const int ko = (kk + 6) * 32;
            #pragma unroll
            for (int i = 0; i < 2; i++) a[cur][i] = *(const short8*)(aP + ko + i * 16 * FDIM);
            #pragma unroll
            for (int j = 0; j < 4; j++) b[cur][j] = *(const short8*)(bP + ko + j * 16 * FDIM);
        }
    }

    #pragma unroll
    for (int i = 0; i < 2; i++) {
        #pragma unroll
        for (int j = 0; j < 4; j++) {
            #pragma unroll
            for (int r = 0; r < 4; r++) {
                const int m = m0 + i * 16 + g * 4 + r;
                const int n = n0 + j * 16 + row;
                const float v = acc[i][j][r];
                if (isB) Bm[(long)(m - NL) * FDIM + n] = v + b1[n];
                else     A [(long)m * FDIM + n] = v;
            }
        }
    }
}

// K3 (pair + final fused): 400 blocks x 256 thr. Wave = ONE full l-row (no
// k-split -> no partials kernel). lane = r.
//  stage: Bm f32 -> bf16-packed LDS, TRANSPOSED XOR layout Bs[u][r^(u&15)]:
//         per-wave reads are 64 consecutive 8B slots (2-way = free); only the
//         32 one-time stage writes are 4-way.
//  loop:  128 iters: 1 ds_read_b64 (B) + 2 wave-uniform VMEM float4 (A row, wd)
//         + 16 VALU. A/wd are L2-hot.
__global__ __launch_bounds__(256) void k_pair(
    const float* __restrict__ A, const float* __restrict__ Bm,
    const float* __restrict__ wd, const float* __restrict__ b2,
    float* __restrict__ out)
{
    __shared__ uint2 Bs[128][64];   // 64 KB
    const int t    = threadIdx.x;
    const int w    = t >> 6;        // 0..3
    const int lane = t & 63;        // r
    const int l    = blockIdx.x * 4 + w;

    const float4* B4 = (const float4*)Bm;
    #pragma unroll
    for (int i = 0; i < 32; ++i) {
        const int g = i * 256 + t;            // 0..8191; consec t -> consec u (coalesced load)
        const int r = g >> 7, u = g & 127;
        float4 v = B4[(long)r * 128 + u];
        unsigned lo = (unsigned)f2bf(v.x) | ((unsigned)f2bf(v.y) << 16);
        unsigned hi = (unsigned)f2bf(v.z) | ((unsigned)f2bf(v.w) << 16);
        Bs[u][r ^ (u & 15)] = make_uint2(lo, hi);
    }
    __syncthreads();

    const float4* Ar = (const float4*)(A + (long)l * FDIM);
    const float4* W4 = (const float4*)wd;
    float s = 0.f;
    #pragma unroll 8
    for (int i = 0; i < 128; ++i) {
        uint2 pk = Bs[i][lane ^ (i & 15)];
        float bx = __uint_as_float(pk.x << 16);
        float by = __uint_as_float(pk.x & 0xffff0000u);
        float bz = __uint_as_float(pk.y << 16);
        float bw = __uint_as_float(pk.y & 0xffff0000u);
        float4 a = Ar[i];
        float4 wv = W4[i];
        s = fmaf(fmaxf(a.x + bx, 0.f), wv.x, s);
        s = fmaf(fmaxf(a.y + by, 0.f), wv.y, s);
        s = fmaf(fmaxf(a.z + bz, 0.f), wv.z, s);
        s = fmaf(fmaxf(a.w + bw, 0.f), wv.w, s);
    }
    const float z = s + (b2[1] - b2[0]);
    out[(long)l * NR + lane] = 1.f / (1.f + expf(-z));
}

extern "C" void kernel_launch(void* const* d_in, const int* in_sizes, int n_in,
                              void* d_out, int out_size, void* d_ws, size_t ws_size,
                              hipStream_t stream) {
    const float* SL  = (const float*)d_in[0];   // [200000,512]
    const float* SR  = (const float*)d_in[1];   // [100000,512]
    const float* W1  = (const float*)d_in[2];   // [1024,512]
    const float* b1  = (const float*)d_in[3];   // [512]
    const float* W2  = (const float*)d_in[4];   // [512,2]
    const float* b2  = (const float*)d_in[5];   // [2]
    const int*   idxL = (const int*)d_in[6];    // [1600]
    const int*   idxR = (const int*)d_in[7];    // [64]
    float* out = (float*)d_out;                 // [1600,64]

    float* A  = (float*)d_ws;                          // [1600,512] f32
    float* Bm = A + (long)NL * FDIM;                   // [64,512]   f32
    float* wd = Bm + (long)NR * FDIM;                  // [512]      f32
    unsigned short* Abf = (unsigned short*)(wd + FDIM);   // [1664,512] bf16
    unsigned short* WT  = Abf + (long)NM * FDIM;          // [2,512,512] bf16

    k_prep<<<929, 256, 0, stream>>>(SL, SR, W1, W2, idxL, idxR, Abf, WT, wd);
    k_mfma<<<dim3(52, 8), 64, 0, stream>>>((const short*)Abf, (const short*)WT, b1, A, Bm);
    k_pair<<<400, 256, 0, stream>>>(A, Bm, wd, b2, out);
}

// Round 10
// 30.005 us; speedup vs baseline: 3.0642x; 1.3450x over previous
//
#include <hip/hip_runtime.h>
#include <math.h>

#define FDIM 512
#define NL 1600
#define NR 64

typedef __attribute__((ext_vector_type(8))) short short8;      // 8 bf16 = 4 VGPR (MFMA A/B frag)
typedef __attribute__((ext_vector_type(4))) float f32x4;       // MFMA C/D frag
typedef __attribute__((ext_vector_type(4))) int   int4v;

__device__ __forceinline__ int cvtpk(float lo, float hi) {
    int r;
    asm("v_cvt_pk_bf16_f32 %0, %1, %2" : "=v"(r) : "v"(lo), "v"(hi));
    return r;   // [15:0]=bf16(lo), [31:16]=bf16(hi), RNE
}

// K1 (direct GEMM, no prep kernel): grid (52,16) x 64 thr (1 wave).
// Tile 32(M) x 32(N), K=512. bm 0..49 -> A rows (W1 top), bm 50..51 -> Bm (+b1).
// A-operand: gathered f32 rows -> v_cvt_pk_bf16_f32 in-register.
// B-operand: W1 columns read directly (8 x dword, stride 2KB) -> packed bf16.
// Both operands use the same slot->k mapping (row=lane&15, k=(lane>>4)*8+j)
// -> consistent bijection, dot product correct. C/D: col=lane&15, row=4*(lane>>4)+r.
__global__ __launch_bounds__(64) void k_gemm(
    const float* __restrict__ SL, const float* __restrict__ SR,
    const float* __restrict__ W1, const float* __restrict__ b1,
    const int* __restrict__ idxL, const int* __restrict__ idxR,
    float* __restrict__ A, float* __restrict__ Bm)
{
    const int bm = blockIdx.x;     // 0..51
    const int bn = blockIdx.y;     // 0..15
    const bool isB = bm >= 50;
    const int n0 = bn * 32;
    const int lane = threadIdx.x, row = lane & 15, g = lane >> 4;

    const float* a0p; const float* a1p;
    if (isB) {
        const int rb = (bm - 50) * 32;
        a0p = SR + (long)idxR[rb + row] * FDIM;
        a1p = SR + (long)idxR[rb + 16 + row] * FDIM;
    } else {
        const int mb = bm * 32;
        a0p = SL + (long)idxL[mb + row] * FDIM;
        a1p = SL + (long)idxL[mb + 16 + row] * FDIM;
    }
    const float* w0 = W1 + (isB ? (long)FDIM * FDIM : 0) + (n0 + row);       // n-frag j=0
    const float* w1 = w0 + 16;                                               // n-frag j=1

    f32x4 acc00 = {}, acc01 = {}, acc10 = {}, acc11 = {};
    float4 a0r[2][2], a1r[2][2];   // [buf][half]
    float  b0r[2][8], b1r[2][8];

    {   // prologue: load k-step 0 into buf 0
        a0r[0][0] = *(const float4*)(a0p + g * 8);
        a0r[0][1] = *(const float4*)(a0p + g * 8 + 4);
        a1r[0][0] = *(const float4*)(a1p + g * 8);
        a1r[0][1] = *(const float4*)(a1p + g * 8 + 4);
        #pragma unroll
        for (int jj = 0; jj < 8; ++jj) {
            b0r[0][jj] = w0[(long)(g * 8 + jj) * FDIM];
            b1r[0][jj] = w1[(long)(g * 8 + jj) * FDIM];
        }
    }

    #pragma unroll
    for (int kk = 0; kk < 16; ++kk) {
        const int cur = kk & 1, nxt = cur ^ 1;     // compile-time after full unroll
        if (kk < 15) {
            const int kb = (kk + 1) * 32 + g * 8;
            a0r[nxt][0] = *(const float4*)(a0p + kb);
            a0r[nxt][1] = *(const float4*)(a0p + kb + 4);
            a1r[nxt][0] = *(const float4*)(a1p + kb);
            a1r[nxt][1] = *(const float4*)(a1p + kb + 4);
            #pragma unroll
            for (int jj = 0; jj < 8; ++jj) {
                b0r[nxt][jj] = w0[(long)(kb + jj) * FDIM];
                b1r[nxt][jj] = w1[(long)(kb + jj) * FDIM];
            }
        }
        int4v a0, a1, b0, b1;
        a0.x = cvtpk(a0r[cur][0].x, a0r[cur][0].y);
        a0.y = cvtpk(a0r[cur][0].z, a0r[cur][0].w);
        a0.z = cvtpk(a0r[cur][1].x, a0r[cur][1].y);
        a0.w = cvtpk(a0r[cur][1].z, a0r[cur][1].w);
        a1.x = cvtpk(a1r[cur][0].x, a1r[cur][0].y);
        a1.y = cvtpk(a1r[cur][0].z, a1r[cur][0].w);
        a1.z = cvtpk(a1r[cur][1].x, a1r[cur][1].y);
        a1.w = cvtpk(a1r[cur][1].z, a1r[cur][1].w);
        b0.x = cvtpk(b0r[cur][0], b0r[cur][1]);
        b0.y = cvtpk(b0r[cur][2], b0r[cur][3]);
        b0.z = cvtpk(b0r[cur][4], b0r[cur][5]);
        b0.w = cvtpk(b0r[cur][6], b0r[cur][7]);
        b1.x = cvtpk(b1r[cur][0], b1r[cur][1]);
        b1.y = cvtpk(b1r[cur][2], b1r[cur][3]);
        b1.z = cvtpk(b1r[cur][4], b1r[cur][5]);
        b1.w = cvtpk(b1r[cur][6], b1r[cur][7]);
        const short8 A0 = *(const short8*)&a0, A1 = *(const short8*)&a1;
        const short8 B0 = *(const short8*)&b0, B1 = *(const short8*)&b1;
        acc00 = __builtin_amdgcn_mfma_f32_16x16x32_bf16(A0, B0, acc00, 0, 0, 0);
        acc01 = __builtin_amdgcn_mfma_f32_16x16x32_bf16(A0, B1, acc01, 0, 0, 0);
        acc10 = __builtin_amdgcn_mfma_f32_16x16x32_bf16(A1, B0, acc10, 0, 0, 0);
        acc11 = __builtin_amdgcn_mfma_f32_16x16x32_bf16(A1, B1, acc11, 0, 0, 0);
    }

    #pragma unroll
    for (int r = 0; r < 4; ++r) {
        const int na = n0 + row, nb = n0 + 16 + row;
        const int mr0 = g * 4 + r, mr1 = 16 + g * 4 + r;   // m within tile
        if (isB) {
            const int rb = (bm - 50) * 32;
            const float ba = b1[na], bb = b1[nb];
            Bm[(long)(rb + mr0) * FDIM + na] = acc00[r] + ba;
            Bm[(long)(rb + mr0) * FDIM + nb] = acc01[r] + bb;
            Bm[(long)(rb + mr1) * FDIM + na] = acc10[r] + ba;
            Bm[(long)(rb + mr1) * FDIM + nb] = acc11[r] + bb;
        } else {
            const int mb = bm * 32;
            A[(long)(mb + mr0) * FDIM + na] = acc00[r];
            A[(long)(mb + mr0) * FDIM + nb] = acc01[r];
            A[(long)(mb + mr1) * FDIM + na] = acc10[r];
            A[(long)(mb + mr1) * FDIM + nb] = acc11[r];
        }
    }
}

// K2 (pair) — R4-proven shape: grid (100, 8) x 256 thr, k-split x8
// (3200 waves = 3.1/SIMD). 16KB Bs chunk [16 k4][64 r] float4, XOR r^c layout.
// Wave = 4 l-rows, lane = r. wd computed per-block from W2 (local slice).
// Part[kq][l][r] = sum_{k in chunk} relu(A[l,k]+B[r,k]) * wd[k]
__global__ __launch_bounds__(256) void k_pair(
    const float* __restrict__ A, const float* __restrict__ Bm,
    const float* __restrict__ W2, float* __restrict__ Part)
{
    __shared__ float4 Bs[16 * 64];   // 16 KB
    __shared__ float wdl[64];
    const int t    = threadIdx.x;
    const int lane = t & 63;
    const int w    = t >> 6;          // wave 0..3
    const int lt   = blockIdx.x;      // 0..99
    const int kq   = blockIdx.y;      // 0..7

    if (t < 32) {   // wd slice for this k-chunk: k = kq*64 + 2t, 2t+1
        float4 v = *(const float4*)(&W2[kq * 128 + 4 * t]);
        wdl[2 * t]     = v.y - v.x;
        wdl[2 * t + 1] = v.w - v.z;
    }
    const float4* Bm4 = (const float4*)Bm;
    #pragma unroll
    for (int i = 0; i < 4; ++i) {
        const int idx = i * 256 + t;          // 0..1023
        const int r = idx >> 4, c = idx & 15;
        Bs[c * 64 + (r ^ c)] = Bm4[r * 128 + kq * 16 + c];
    }
    __syncthreads();

    const int lb = lt * 16 + w * 4;
    const float4* A0 = (const float4*)(A + (long)(lb + 0) * FDIM) + kq * 16;
    const float4* A1 = (const float4*)(A + (long)(lb + 1) * FDIM) + kq * 16;
    const float4* A2 = (const float4*)(A + (long)(lb + 2) * FDIM) + kq * 16;
    const float4* A3 = (const float4*)(A + (long)(lb + 3) * FDIM) + kq * 16;
    const float4* W4 = (const float4*)wdl;

    float acc0 = 0.f, acc1 = 0.f, acc2 = 0.f, acc3 = 0.f;
    #pragma unroll
    for (int c = 0; c < 16; ++c) {
        float4 b  = Bs[c * 64 + (lane ^ c)];
        float4 wv = W4[c];
        float4 a0 = A0[c], a1 = A1[c], a2 = A2[c], a3 = A3[c];
        acc0 = fmaf(fmaxf(a0.x + b.x, 0.f), wv.x, acc0);
        acc0 = fmaf(fmaxf(a0.y + b.y, 0.f), wv.y, acc0);
        acc0 = fmaf(fmaxf(a0.z + b.z, 0.f), wv.z, acc0);
        acc0 = fmaf(fmaxf(a0.w + b.w, 0.f), wv.w, acc0);
        acc1 = fmaf(fmaxf(a1.x + b.x, 0.f), wv.x, acc1);
        acc1 = fmaf(fmaxf(a1.y + b.y, 0.f), wv.y, acc1);
        acc1 = fmaf(fmaxf(a1.z + b.z, 0.f), wv.z, acc1);
        acc1 = fmaf(fmaxf(a1.w + b.w, 0.f), wv.w, acc1);
        acc2 = fmaf(fmaxf(a2.x + b.x, 0.f), wv.x, acc2);
        acc2 = fmaf(fmaxf(a2.y + b.y, 0.f), wv.y, acc2);
        acc2 = fmaf(fmaxf(a2.z + b.z, 0.f), wv.z, acc2);
        acc2 = fmaf(fmaxf(a2.w + b.w, 0.f), wv.w, acc2);
        acc3 = fmaf(fmaxf(a3.x + b.x, 0.f), wv.x, acc3);
        acc3 = fmaf(fmaxf(a3.y + b.y, 0.f), wv.y, acc3);
        acc3 = fmaf(fmaxf(a3.z + b.z, 0.f), wv.z, acc3);
        acc3 = fmaf(fmaxf(a3.w + b.w, 0.f), wv.w, acc3);
    }
    float* P = Part + ((long)kq * NL + lb) * NR + lane;
    P[0 * NR] = acc0;
    P[1 * NR] = acc1;
    P[2 * NR] = acc2;
    P[3 * NR] = acc3;
}

// K3: sum the 8 k-chunk partials + sigmoid (R4 verbatim).
__global__ __launch_bounds__(256) void k_final(
    const float* __restrict__ Part, const float* __restrict__ b2,
    float* __restrict__ out)
{
    const int gid = blockIdx.x * 256 + threadIdx.x;   // 0..102399
    float s = b2[1] - b2[0];
    #pragma unroll
    for (int q = 0; q < 8; ++q) s += Part[(long)q * NL * NR + gid];
    out[gid] = 1.f / (1.f + expf(-s));
}

extern "C" void kernel_launch(void* const* d_in, const int* in_sizes, int n_in,
                              void* d_out, int out_size, void* d_ws, size_t ws_size,
                              hipStream_t stream) {
    const float* SL  = (const float*)d_in[0];   // [200000,512]
    const float* SR  = (const float*)d_in[1];   // [100000,512]
    const float* W1  = (const float*)d_in[2];   // [1024,512]
    const float* b1  = (const float*)d_in[3];   // [512]
    const float* W2  = (const float*)d_in[4];   // [512,2]
    const float* b2  = (const float*)d_in[5];   // [2]
    const int*   idxL = (const int*)d_in[6];    // [1600]
    const int*   idxR = (const int*)d_in[7];    // [64]
    float* out = (float*)d_out;                 // [1600,64]

    float* A    = (float*)d_ws;                 // [1600,512] f32
    float* Bm   = A + (long)NL * FDIM;          // [64,512]   f32
    float* Part = Bm + (long)NR * FDIM;         // [8,1600,64] f32

    k_gemm<<<dim3(52, 16), 64, 0, stream>>>(SL, SR, W1, b1, idxL, idxR, A, Bm);
    k_pair<<<dim3(100, 8), 256, 0, stream>>>(A, Bm, W2, Part);
    k_final<<<(NL * NR) / 256, 256, 0, stream>>>(Part, b2, out);
}

// Round 12
// 28.591 us; speedup vs baseline: 3.2157x; 1.0495x over previous
//
#include <hip/hip_runtime.h>
#include <math.h>

#define FDIM 512
#define NL 1600
#define NR 64

typedef __attribute__((ext_vector_type(8))) short short8;      // 8 bf16 = 4 VGPR (MFMA A/B frag)
typedef __attribute__((ext_vector_type(4))) float f32x4;       // MFMA C/D frag
typedef __attribute__((ext_vector_type(4))) int   int4v;

__device__ __forceinline__ int cvtpk(float lo, float hi) {
    int r;
    asm("v_cvt_pk_bf16_f32 %0, %1, %2" : "=v"(r) : "v"(lo), "v"(hi));
    return r;   // [15:0]=bf16(lo), [31:16]=bf16(hi), RNE
}

// K1 (direct GEMM) — R10-proven VERBATIM. grid (52,16) x 64 thr (1 wave).
// Tile 32(M) x 32(N), K=512. bm 0..49 -> A rows (W1 top), bm 50..51 -> Bm (+b1).
// A-operand: gathered f32 rows -> v_cvt_pk_bf16_f32 in-register.
// B-operand: W1 columns read directly (8 x dword, stride 2KB) -> packed bf16.
// Both operands use the same slot->k mapping (row=lane&15, k=(lane>>4)*8+j)
// -> consistent bijection, dot product correct. C/D: col=lane&15, row=4*(lane>>4)+r.
__global__ __launch_bounds__(64) void k_gemm(
    const float* __restrict__ SL, const float* __restrict__ SR,
    const float* __restrict__ W1, const float* __restrict__ b1,
    const int* __restrict__ idxL, const int* __restrict__ idxR,
    float* __restrict__ A, float* __restrict__ Bm)
{
    const int bm = blockIdx.x;     // 0..51
    const int bn = blockIdx.y;     // 0..15
    const bool isB = bm >= 50;
    const int n0 = bn * 32;
    const int lane = threadIdx.x, row = lane & 15, g = lane >> 4;

    const float* a0p; const float* a1p;
    if (isB) {
        const int rb = (bm - 50) * 32;
        a0p = SR + (long)idxR[rb + row] * FDIM;
        a1p = SR + (long)idxR[rb + 16 + row] * FDIM;
    } else {
        const int mb = bm * 32;
        a0p = SL + (long)idxL[mb + row] * FDIM;
        a1p = SL + (long)idxL[mb + 16 + row] * FDIM;
    }
    const float* w0 = W1 + (isB ? (long)FDIM * FDIM : 0) + (n0 + row);       // n-frag j=0
    const float* w1 = w0 + 16;                                               // n-frag j=1

    f32x4 acc00 = {}, acc01 = {}, acc10 = {}, acc11 = {};
    float4 a0r[2][2], a1r[2][2];   // [buf][half]
    float  b0r[2][8], b1r[2][8];

    {   // prologue: load k-step 0 into buf 0
        a0r[0][0] = *(const float4*)(a0p + g * 8);
        a0r[0][1] = *(const float4*)(a0p + g * 8 + 4);
        a1r[0][0] = *(const float4*)(a1p + g * 8);
        a1r[0][1] = *(const float4*)(a1p + g * 8 + 4);
        #pragma unroll
        for (int jj = 0; jj < 8; ++jj) {
            b0r[0][jj] = w0[(long)(g * 8 + jj) * FDIM];
            b1r[0][jj] = w1[(long)(g * 8 + jj) * FDIM];
        }
    }

    #pragma unroll
    for (int kk = 0; kk < 16; ++kk) {
        const int cur = kk & 1, nxt = cur ^ 1;     // compile-time after full unroll
        if (kk < 15) {
            const int kb = (kk + 1) * 32 + g * 8;
            a0r[nxt][0] = *(const float4*)(a0p + kb);
            a0r[nxt][1] = *(const float4*)(a0p + kb + 4);
            a1r[nxt][0] = *(const float4*)(a1p + kb);
            a1r[nxt][1] = *(const float4*)(a1p + kb + 4);
            #pragma unroll
            for (int jj = 0; jj < 8; ++jj) {
                b0r[nxt][jj] = w0[(long)(kb + jj) * FDIM];
                b1r[nxt][jj] = w1[(long)(kb + jj) * FDIM];
            }
        }
        int4v a0, a1, b0, b1;
        a0.x = cvtpk(a0r[cur][0].x, a0r[cur][0].y);
        a0.y = cvtpk(a0r[cur][0].z, a0r[cur][0].w);
        a0.z = cvtpk(a0r[cur][1].x, a0r[cur][1].y);
        a0.w = cvtpk(a0r[cur][1].z, a0r[cur][1].w);
        a1.x = cvtpk(a1r[cur][0].x, a1r[cur][0].y);
        a1.y = cvtpk(a1r[cur][0].z, a1r[cur][0].w);
        a1.z = cvtpk(a1r[cur][1].x, a1r[cur][1].y);
        a1.w = cvtpk(a1r[cur][1].z, a1r[cur][1].w);
        b0.x = cvtpk(b0r[cur][0], b0r[cur][1]);
        b0.y = cvtpk(b0r[cur][2], b0r[cur][3]);
        b0.z = cvtpk(b0r[cur][4], b0r[cur][5]);
        b0.w = cvtpk(b0r[cur][6], b0r[cur][7]);
        b1.x = cvtpk(b1r[cur][0], b1r[cur][1]);
        b1.y = cvtpk(b1r[cur][2], b1r[cur][3]);
        b1.z = cvtpk(b1r[cur][4], b1r[cur][5]);
        b1.w = cvtpk(b1r[cur][6], b1r[cur][7]);
        const short8 A0 = *(const short8*)&a0, A1 = *(const short8*)&a1;
        const short8 B0 = *(const short8*)&b0, B1 = *(const short8*)&b1;
        acc00 = __builtin_amdgcn_mfma_f32_16x16x32_bf16(A0, B0, acc00, 0, 0, 0);
        acc01 = __builtin_amdgcn_mfma_f32_16x16x32_bf16(A0, B1, acc01, 0, 0, 0);
        acc10 = __builtin_amdgcn_mfma_f32_16x16x32_bf16(A1, B0, acc10, 0, 0, 0);
        acc11 = __builtin_amdgcn_mfma_f32_16x16x32_bf16(A1, B1, acc11, 0, 0, 0);
    }

    #pragma unroll
    for (int r = 0; r < 4; ++r) {
        const int na = n0 + row, nb = n0 + 16 + row;
        const int mr0 = g * 4 + r, mr1 = 16 + g * 4 + r;   // m within tile
        if (isB) {
            const int rb = (bm - 50) * 32;
            const float ba = b1[na], bb = b1[nb];
            Bm[(long)(rb + mr0) * FDIM + na] = acc00[r] + ba;
            Bm[(long)(rb + mr0) * FDIM + nb] = acc01[r] + bb;
            Bm[(long)(rb + mr1) * FDIM + na] = acc10[r] + ba;
            Bm[(long)(rb + mr1) * FDIM + nb] = acc11[r] + bb;
        } else {
            const int mb = bm * 32;
            A[(long)(mb + mr0) * FDIM + na] = acc00[r];
            A[(long)(mb + mr0) * FDIM + nb] = acc01[r];
            A[(long)(mb + mr1) * FDIM + na] = acc10[r];
            A[(long)(mb + mr1) * FDIM + nb] = acc11[r];
        }
    }
}

// K2 (pair + final, wave-level k-split): 400 blocks x 512 thr (8 waves).
// Block = 4 l-rows; wave w = k-chunk kq=w. Full Bm staged ONCE per block as
// bf16-packed LDS (64 KB, XOR layout Bs[u][r^(u&15)]); wd in LDS (2 KB,
// staged by t<256 — R11 bug was t<128 leaving half of wdl poisoned).
// Partials reduced via LDS aliased over Bs after sync + sigmoid -> out.
__global__ __launch_bounds__(512) void k_pair(
    const float* __restrict__ A, const float* __restrict__ Bm,
    const float* __restrict__ W2, const float* __restrict__ b2,
    float* __restrict__ out)
{
    __shared__ uint2 Bs[128][64];   // 64 KB; aliased as Part[8][4][64] f32 in epilogue
    __shared__ float wdl[FDIM];     // 2 KB
    const int t    = threadIdx.x;
    const int w    = t >> 6;        // wave 0..7 = k-chunk
    const int lane = t & 63;        // r
    const int lb   = blockIdx.x * 4;

    // stage wd: wdl[k] = W2[k][1] - W2[k][0]  (256 threads x 2 entries = 512)
    if (t < 256) {
        float4 v = *(const float4*)(&W2[t * 4]);   // k = 2t, 2t+1
        wdl[2 * t]     = v.y - v.x;
        wdl[2 * t + 1] = v.w - v.z;
    }
    // stage full Bm -> bf16-packed XOR layout (one-time; writes 4-way banked)
    const float4* B4 = (const float4*)Bm;
    #pragma unroll
    for (int i = 0; i < 16; ++i) {
        const int g = i * 512 + t;          // 0..8191; consec t -> consec u (coalesced)
        const int r = g >> 7, u = g & 127;
        float4 v = B4[(long)r * 128 + u];
        uint2 pk;
        pk.x = (unsigned)cvtpk(v.x, v.y);
        pk.y = (unsigned)cvtpk(v.z, v.w);
        Bs[u][r ^ (u & 15)] = pk;
    }
    __syncthreads();

    // compute: wave w handles k = w*64 .. w*64+63 for the block's 4 l-rows
    const float4* A0 = (const float4*)(A + (long)(lb + 0) * FDIM) + w * 16;
    const float4* A1 = (const float4*)(A + (long)(lb + 1) * FDIM) + w * 16;
    const float4* A2 = (const float4*)(A + (long)(lb + 2) * FDIM) + w * 16;
    const float4* A3 = (const float4*)(A + (long)(lb + 3) * FDIM) + w * 16;
    const float4* W4 = (const float4*)wdl + w * 16;

    float acc0 = 0.f, acc1 = 0.f, acc2 = 0.f, acc3 = 0.f;
    #pragma unroll
    for (int c = 0; c < 16; ++c) {
        const int u = w * 16 + c;
        uint2 pk = Bs[u][lane ^ (u & 15)];
        float bx = __uint_as_float(pk.x << 16);
        float by = __uint_as_float(pk.x & 0xffff0000u);
        float bz = __uint_as_float(pk.y << 16);
        float bw = __uint_as_float(pk.y & 0xffff0000u);
        float4 wv = W4[c];
        float4 a0 = A0[c], a1 = A1[c], a2 = A2[c], a3 = A3[c];
        acc0 = fmaf(fmaxf(a0.x + bx, 0.f), wv.x, acc0);
        acc0 = fmaf(fmaxf(a0.y + by, 0.f), wv.y, acc0);
        acc0 = fmaf(fmaxf(a0.z + bz, 0.f), wv.z, acc0);
        acc0 = fmaf(fmaxf(a0.w + bw, 0.f), wv.w, acc0);
        acc1 = fmaf(fmaxf(a1.x + bx, 0.f), wv.x, acc1);
        acc1 = fmaf(fmaxf(a1.y + by, 0.f), wv.y, acc1);
        acc1 = fmaf(fmaxf(a1.z + bz, 0.f), wv.z, acc1);
        acc1 = fmaf(fmaxf(a1.w + bw, 0.f), wv.w, acc1);
        acc2 = fmaf(fmaxf(a2.x + bx, 0.f), wv.x, acc2);
        acc2 = fmaf(fmaxf(a2.y + by, 0.f), wv.y, acc2);
        acc2 = fmaf(fmaxf(a2.z + bz, 0.f), wv.z, acc2);
        acc2 = fmaf(fmaxf(a2.w + bw, 0.f), wv.w, acc2);
        acc3 = fmaf(fmaxf(a3.x + bx, 0.f), wv.x, acc3);
        acc3 = fmaf(fmaxf(a3.y + by, 0.f), wv.y, acc3);
        acc3 = fmaf(fmaxf(a3.z + bz, 0.f), wv.z, acc3);
        acc3 = fmaf(fmaxf(a3.w + bw, 0.f), wv.w, acc3);
    }
    __syncthreads();                 // all Bs reads done before aliasing
    float* P = (float*)Bs;           // Part[w][li][r] = [8][4][64]
    {
        const int base = (w * 4) * 64 + lane;
        P[base]       = acc0;
        P[base + 64]  = acc1;
        P[base + 128] = acc2;
        P[base + 192] = acc3;
    }
    __syncthreads();

    // epilogue: fixed-order reduce over the 8 chunks + sigmoid
    if (t < 256) {
        const int li = t >> 6, rr = t & 63;
        float s = b2[1] - b2[0];
        #pragma unroll
        for (int q = 0; q < 8; ++q)
            s += P[(q * 4 + li) * 64 + rr];
        out[(long)(lb + li) * NR + rr] = 1.f / (1.f + expf(-s));
    }
}

extern "C" void kernel_launch(void* const* d_in, const int* in_sizes, int n_in,
                              void* d_out, int out_size, void* d_ws, size_t ws_size,
                              hipStream_t stream) {
    const float* SL  = (const float*)d_in[0];   // [200000,512]
    const float* SR  = (const float*)d_in[1];   // [100000,512]
    const float* W1  = (const float*)d_in[2];   // [1024,512]
    const float* b1  = (const float*)d_in[3];   // [512]
    const float* W2  = (const float*)d_in[4];   // [512,2]
    const float* b2  = (const float*)d_in[5];   // [2]
    const int*   idxL = (const int*)d_in[6];    // [1600]
    const int*   idxR = (const int*)d_in[7];    // [64]
    float* out = (float*)d_out;                 // [1600,64]

    float* A  = (float*)d_ws;                   // [1600,512] f32
    float* Bm = A + (long)NL * FDIM;            // [64,512]   f32

    k_gemm<<<dim3(52, 16), 64, 0, stream>>>(SL, SR, W1, b1, idxL, idxR, A, Bm);
    k_pair<<<NL / 4, 512, 0, stream>>>(A, Bm, W2, b2, out);
}

// Round 13
// 28.455 us; speedup vs baseline: 3.2311x; 1.0048x over previous
//
#include <hip/hip_runtime.h>
#include <math.h>

#define FDIM 512
#define NL 1600
#define NR 64

typedef __attribute__((ext_vector_type(8))) short short8;      // 8 bf16 = 4 VGPR (MFMA A/B frag)
typedef __attribute__((ext_vector_type(4))) float f32x4;       // MFMA C/D frag
typedef __attribute__((ext_vector_type(4))) int   int4v;

__device__ __forceinline__ int cvtpk(float lo, float hi) {
    int r;
    asm("v_cvt_pk_bf16_f32 %0, %1, %2" : "=v"(r) : "v"(lo), "v"(hi));
    return r;   // [15:0]=bf16(lo), [31:16]=bf16(hi), RNE
}

// K1 (direct GEMM): grid (52,16) x 64 thr (1 wave). Tile 32(M) x 32(N), K=512.
// R12 structure with DEPTH-3 register pipeline (prefetch distance 2 k-steps
// ~ 300cy of issue between load and consume, covering L2 latency at 0.8
// waves/SIMD occupancy). bm 0..49 -> A rows (W1 top), bm 50..51 -> Bm (+b1).
// A-operand: gathered f32 rows -> v_cvt_pk_bf16_f32 in-register.
// B-operand: W1 columns read directly (8 x dword, stride 2KB) -> packed bf16.
// Same slot->k mapping for A and B (row=lane&15, k=(lane>>4)*8+j) -> correct
// dot product; C/D: col=lane&15, row=4*(lane>>4)+r.
__global__ __launch_bounds__(64) void k_gemm(
    const float* __restrict__ SL, const float* __restrict__ SR,
    const float* __restrict__ W1, const float* __restrict__ b1,
    const int* __restrict__ idxL, const int* __restrict__ idxR,
    float* __restrict__ A, float* __restrict__ Bm)
{
    const int bm = blockIdx.x;     // 0..51
    const int bn = blockIdx.y;     // 0..15
    const bool isB = bm >= 50;
    const int n0 = bn * 32;
    const int lane = threadIdx.x, row = lane & 15, g = lane >> 4;

    const float* a0p; const float* a1p;
    if (isB) {
        const int rb = (bm - 50) * 32;
        a0p = SR + (long)idxR[rb + row] * FDIM;
        a1p = SR + (long)idxR[rb + 16 + row] * FDIM;
    } else {
        const int mb = bm * 32;
        a0p = SL + (long)idxL[mb + row] * FDIM;
        a1p = SL + (long)idxL[mb + 16 + row] * FDIM;
    }
    const float* w0 = W1 + (isB ? (long)FDIM * FDIM : 0) + (n0 + row);       // n-frag j=0
    const float* w1 = w0 + 16;                                               // n-frag j=1

    f32x4 acc00 = {}, acc01 = {}, acc10 = {}, acc11 = {};
    float4 a0r[3][2], a1r[3][2];   // [buf][half]
    float  b0r[3][8], b1r[3][8];

    // prologue: load k-steps 0,1 into bufs 0,1 (prefetch distance 2)
    #pragma unroll
    for (int s = 0; s < 2; ++s) {
        const int kb = s * 32 + g * 8;
        a0r[s][0] = *(const float4*)(a0p + kb);
        a0r[s][1] = *(const float4*)(a0p + kb + 4);
        a1r[s][0] = *(const float4*)(a1p + kb);
        a1r[s][1] = *(const float4*)(a1p + kb + 4);
        #pragma unroll
        for (int jj = 0; jj < 8; ++jj) {
            b0r[s][jj] = w0[(long)(kb + jj) * FDIM];
            b1r[s][jj] = w1[(long)(kb + jj) * FDIM];
        }
    }

    #pragma unroll
    for (int kk = 0; kk < 16; ++kk) {
        const int cur = kk % 3;                      // compile-time after full unroll
        if (kk < 14) {
            const int nxt = (kk + 2) % 3;            // buf freed at step kk-1
            const int kb = (kk + 2) * 32 + g * 8;
            a0r[nxt][0] = *(const float4*)(a0p + kb);
            a0r[nxt][1] = *(const float4*)(a0p + kb + 4);
            a1r[nxt][0] = *(const float4*)(a1p + kb);
            a1r[nxt][1] = *(const float4*)(a1p + kb + 4);
            #pragma unroll
            for (int jj = 0; jj < 8; ++jj) {
                b0r[nxt][jj] = w0[(long)(kb + jj) * FDIM];
                b1r[nxt][jj] = w1[(long)(kb + jj) * FDIM];
            }
        }
        int4v a0, a1, b0, b1;
        a0.x = cvtpk(a0r[cur][0].x, a0r[cur][0].y);
        a0.y = cvtpk(a0r[cur][0].z, a0r[cur][0].w);
        a0.z = cvtpk(a0r[cur][1].x, a0r[cur][1].y);
        a0.w = cvtpk(a0r[cur][1].z, a0r[cur][1].w);
        a1.x = cvtpk(a1r[cur][0].x, a1r[cur][0].y);
        a1.y = cvtpk(a1r[cur][0].z, a1r[cur][0].w);
        a1.z = cvtpk(a1r[cur][1].x, a1r[cur][1].y);
        a1.w = cvtpk(a1r[cur][1].z, a1r[cur][1].w);
        b0.x = cvtpk(b0r[cur][0], b0r[cur][1]);
        b0.y = cvtpk(b0r[cur][2], b0r[cur][3]);
        b0.z = cvtpk(b0r[cur][4], b0r[cur][5]);
        b0.w = cvtpk(b0r[cur][6], b0r[cur][7]);
        b1.x = cvtpk(b1r[cur][0], b1r[cur][1]);
        b1.y = cvtpk(b1r[cur][2], b1r[cur][3]);
        b1.z = cvtpk(b1r[cur][4], b1r[cur][5]);
        b1.w = cvtpk(b1r[cur][6], b1r[cur][7]);
        const short8 A0 = *(const short8*)&a0, A1 = *(const short8*)&a1;
        const short8 B0 = *(const short8*)&b0, B1 = *(const short8*)&b1;
        acc00 = __builtin_amdgcn_mfma_f32_16x16x32_bf16(A0, B0, acc00, 0, 0, 0);
        acc01 = __builtin_amdgcn_mfma_f32_16x16x32_bf16(A0, B1, acc01, 0, 0, 0);
        acc10 = __builtin_amdgcn_mfma_f32_16x16x32_bf16(A1, B0, acc10, 0, 0, 0);
        acc11 = __builtin_amdgcn_mfma_f32_16x16x32_bf16(A1, B1, acc11, 0, 0, 0);
    }

    #pragma unroll
    for (int r = 0; r < 4; ++r) {
        const int na = n0 + row, nb = n0 + 16 + row;
        const int mr0 = g * 4 + r, mr1 = 16 + g * 4 + r;   // m within tile
        if (isB) {
            const int rb = (bm - 50) * 32;
            const float ba = b1[na], bb = b1[nb];
            Bm[(long)(rb + mr0) * FDIM + na] = acc00[r] + ba;
            Bm[(long)(rb + mr0) * FDIM + nb] = acc01[r] + bb;
            Bm[(long)(rb + mr1) * FDIM + na] = acc10[r] + ba;
            Bm[(long)(rb + mr1) * FDIM + nb] = acc11[r] + bb;
        } else {
            const int mb = bm * 32;
            A[(long)(mb + mr0) * FDIM + na] = acc00[r];
            A[(long)(mb + mr0) * FDIM + nb] = acc01[r];
            A[(long)(mb + mr1) * FDIM + na] = acc10[r];
            A[(long)(mb + mr1) * FDIM + nb] = acc11[r];
        }
    }
}

// K2 (pair + final, wave-level k-split) — R12-proven VERBATIM.
// 400 blocks x 512 thr (8 waves). Block = 4 l-rows; wave w = k-chunk kq=w.
// Full Bm staged ONCE per block as bf16-packed LDS (64 KB, XOR layout
// Bs[u][r^(u&15)]); wd in LDS (2 KB, staged by t<256). Partials reduced via
// LDS aliased over Bs after sync + sigmoid -> out.
__global__ __launch_bounds__(512) void k_pair(
    const float* __restrict__ A, const float* __restrict__ Bm,
    const float* __restrict__ W2, const float* __restrict__ b2,
    float* __restrict__ out)
{
    __shared__ uint2 Bs[128][64];   // 64 KB; aliased as Part[8][4][64] f32 in epilogue
    __shared__ float wdl[FDIM];     // 2 KB
    const int t    = threadIdx.x;
    const int w    = t >> 6;        // wave 0..7 = k-chunk
    const int lane = t & 63;        // r
    const int lb   = blockIdx.x * 4;

    // stage wd: wdl[k] = W2[k][1] - W2[k][0]  (256 threads x 2 entries = 512)
    if (t < 256) {
        float4 v = *(const float4*)(&W2[t * 4]);   // k = 2t, 2t+1
        wdl[2 * t]     = v.y - v.x;
        wdl[2 * t + 1] = v.w - v.z;
    }
    // stage full Bm -> bf16-packed XOR layout (one-time; writes 4-way banked)
    const float4* B4 = (const float4*)Bm;
    #pragma unroll
    for (int i = 0; i < 16; ++i) {
        const int g = i * 512 + t;          // 0..8191; consec t -> consec u (coalesced)
        const int r = g >> 7, u = g & 127;
        float4 v = B4[(long)r * 128 + u];
        uint2 pk;
        pk.x = (unsigned)cvtpk(v.x, v.y);
        pk.y = (unsigned)cvtpk(v.z, v.w);
        Bs[u][r ^ (u & 15)] = pk;
    }
    __syncthreads();

    // compute: wave w handles k = w*64 .. w*64+63 for the block's 4 l-rows
    const float4* A0 = (const float4*)(A + (long)(lb + 0) * FDIM) + w * 16;
    const float4* A1 = (const float4*)(A + (long)(lb + 1) * FDIM) + w * 16;
    const float4* A2 = (const float4*)(A + (long)(lb + 2) * FDIM) + w * 16;
    const float4* A3 = (const float4*)(A + (long)(lb + 3) * FDIM) + w * 16;
    const float4* W4 = (const float4*)wdl + w * 16;

    float acc0 = 0.f, acc1 = 0.f, acc2 = 0.f, acc3 = 0.f;
    #pragma unroll
    for (int c = 0; c < 16; ++c) {
        const int u = w * 16 + c;
        uint2 pk = Bs[u][lane ^ (u & 15)];
        float bx = __uint_as_float(pk.x << 16);
        float by = __uint_as_float(pk.x & 0xffff0000u);
        float bz = __uint_as_float(pk.y << 16);
        float bw = __uint_as_float(pk.y & 0xffff0000u);
        float4 wv = W4[c];
        float4 a0 = A0[c], a1 = A1[c], a2 = A2[c], a3 = A3[c];
        acc0 = fmaf(fmaxf(a0.x + bx, 0.f), wv.x, acc0);
        acc0 = fmaf(fmaxf(a0.y + by, 0.f), wv.y, acc0);
        acc0 = fmaf(fmaxf(a0.z + bz, 0.f), wv.z, acc0);
        acc0 = fmaf(fmaxf(a0.w + bw, 0.f), wv.w, acc0);
        acc1 = fmaf(fmaxf(a1.x + bx, 0.f), wv.x, acc1);
        acc1 = fmaf(fmaxf(a1.y + by, 0.f), wv.y, acc1);
        acc1 = fmaf(fmaxf(a1.z + bz, 0.f), wv.z, acc1);
        acc1 = fmaf(fmaxf(a1.w + bw, 0.f), wv.w, acc1);
        acc2 = fmaf(fmaxf(a2.x + bx, 0.f), wv.x, acc2);
        acc2 = fmaf(fmaxf(a2.y + by, 0.f), wv.y, acc2);
        acc2 = fmaf(fmaxf(a2.z + bz, 0.f), wv.z, acc2);
        acc2 = fmaf(fmaxf(a2.w + bw, 0.f), wv.w, acc2);
        acc3 = fmaf(fmaxf(a3.x + bx, 0.f), wv.x, acc3);
        acc3 = fmaf(fmaxf(a3.y + by, 0.f), wv.y, acc3);
        acc3 = fmaf(fmaxf(a3.z + bz, 0.f), wv.z, acc3);
        acc3 = fmaf(fmaxf(a3.w + bw, 0.f), wv.w, acc3);
    }
    __syncthreads();                 // all Bs reads done before aliasing
    float* P = (float*)Bs;           // Part[w][li][r] = [8][4][64]
    {
        const int base = (w * 4) * 64 + lane;
        P[base]       = acc0;
        P[base + 64]  = acc1;
        P[base + 128] = acc2;
        P[base + 192] = acc3;
    }
    __syncthreads();

    // epilogue: fixed-order reduce over the 8 chunks + sigmoid
    if (t < 256) {
        const int li = t >> 6, rr = t & 63;
        float s = b2[1] - b2[0];
        #pragma unroll
        for (int q = 0; q < 8; ++q)
            s += P[(q * 4 + li) * 64 + rr];
        out[(long)(lb + li) * NR + rr] = 1.f / (1.f + expf(-s));
    }
}

extern "C" void kernel_launch(void* const* d_in, const int* in_sizes, int n_in,
                              void* d_out, int out_size, void* d_ws, size_t ws_size,
                              hipStream_t stream) {
    const float* SL  = (const float*)d_in[0];   // [200000,512]
    const float* SR  = (const float*)d_in[1];   // [100000,512]
    const float* W1  = (const float*)d_in[2];   // [1024,512]
    const float* b1  = (const float*)d_in[3];   // [512]
    const float* W2  = (const float*)d_in[4];   // [512,2]
    const float* b2  = (const float*)d_in[5];   // [2]
    const int*   idxL = (const int*)d_in[6];    // [1600]
    const int*   idxR = (const int*)d_in[7];    // [64]
    float* out = (float*)d_out;                 // [1600,64]

    float* A  = (float*)d_ws;                   // [1600,512] f32
    float* Bm = A + (long)NL * FDIM;            // [64,512]   f32

    k_gemm<<<dim3(52, 16), 64, 0, stream>>>(SL, SR, W1, b1, idxL, idxR, A, Bm);
    k_pair<<<NL / 4, 512, 0, stream>>>(A, Bm, W2, b2, out);
}